// Round 5
// baseline (470.956 us; speedup 1.0000x reference)
//
#include <hip/hip_runtime.h>

#define B_  2
#define T_  1024
#define D_  2048
#define NH  16
#define KH  4
#define HD  128
#define TC_ 1024
#define S_  2048

typedef __bf16 bf16x4v __attribute__((ext_vector_type(4)));
typedef __bf16 bf16x8v __attribute__((ext_vector_type(8)));
typedef float  f32x4v  __attribute__((ext_vector_type(4)));

__device__ __forceinline__ void async_copy16(void* lds, const void* g) {
    __builtin_amdgcn_global_load_lds(
        (__attribute__((address_space(1))) void*)g,
        (__attribute__((address_space(3))) void*)lds, 16, 0, 0);
}

// ---------------- x fp32 -> bf16 ----------------
__global__ void cvt_x(const float* __restrict__ x, __bf16* __restrict__ xb) {
    int i = (blockIdx.x * 256 + threadIdx.x) * 4;
    float4 v = *(const float4*)(x + i);
    bf16x4v o; o[0]=(__bf16)v.x; o[1]=(__bf16)v.y; o[2]=(__bf16)v.z; o[3]=(__bf16)v.w;
    *(bf16x4v*)(xb + i) = o;
}

// ---------------- weight transposes ----------------
__global__ void tp_w(const float* __restrict__ in, __bf16* __restrict__ out) {
    __shared__ float tile[32][33];
    int h0 = blockIdx.x * 32;
    int d0 = blockIdx.y * 32;
    const float* ip = in + (size_t)blockIdx.z * (D_ * HD);
    __bf16* op = out + (size_t)blockIdx.z * (D_ * HD);
    int tx = threadIdx.x, ty = threadIdx.y;
    for (int i = 0; i < 32; i += 8)
        tile[ty + i][tx] = ip[(size_t)(d0 + ty + i) * HD + h0 + tx];
    __syncthreads();
    for (int i = 0; i < 32; i += 8)
        op[(size_t)(h0 + ty + i) * D_ + d0 + tx] = (__bf16)tile[tx][ty + i];
}

__global__ void tp_wout(const float* __restrict__ in, __bf16* __restrict__ out) {
    __shared__ float tile[32][33];
    int d0 = blockIdx.x * 32;
    int h0 = blockIdx.y * 32;
    int n  = blockIdx.z;
    const float* ip = in + (size_t)n * (HD * D_);
    int tx = threadIdx.x, ty = threadIdx.y;
    for (int i = 0; i < 32; i += 8)
        tile[ty + i][tx] = ip[(size_t)(h0 + ty + i) * D_ + d0 + tx];
    __syncthreads();
    for (int i = 0; i < 32; i += 8)
        out[(size_t)(d0 + ty + i) * (NH * HD) + n * HD + h0 + tx] = (__bf16)tile[tx][ty + i];
}

// cache_v fp32 [B][TC][K][H] -> vtb bf16 [B][K][H][S] (s<TC half only)
__global__ void tp_v(const float* __restrict__ cv, __bf16* __restrict__ vtb) {
    __shared__ float tile[32][33];
    int z = blockIdx.z; int b = z / KH, kh = z % KH;
    int h0 = blockIdx.x * 32;
    int s0 = blockIdx.y * 32;          // 0..1023
    const float* ip = cv + ((size_t)b * TC_ * KH + kh) * HD;
    int tx = threadIdx.x, ty = threadIdx.y;
    for (int i = 0; i < 32; i += 8)
        tile[ty + i][tx] = ip[(size_t)(s0 + ty + i) * (KH * HD) + h0 + tx];
    __syncthreads();
    __bf16* op = vtb + ((size_t)b * KH + kh) * (size_t)HD * S_;
    for (int i = 0; i < 32; i += 8)
        op[(size_t)(h0 + ty + i) * S_ + s0 + tx] = (__bf16)tile[tx][ty + i];
}

// ---------------- cache copy (fp32 exact) + bf16 K-cache ----------------
__global__ void copy_cache(const float4* __restrict__ ck, const float4* __restrict__ cv,
                           float* __restrict__ kout, float* __restrict__ vout,
                           __bf16* __restrict__ kb) {
    int i = blockIdx.x * 256 + threadIdx.x;     // 262144 total
    int b = i >> 17;
    int r = i & 131071;
    float4 kv = ck[i];
    ((float4*)(kout + (size_t)b * S_ * KH * HD))[r] = kv;
    ((float4*)(vout + (size_t)b * S_ * KH * HD))[r] = cv[i];
    int h4 = r & 31;
    int kh = (r >> 5) & 3;
    int s  = r >> 7;
    bf16x4v o; o[0]=(__bf16)kv.x; o[1]=(__bf16)kv.y; o[2]=(__bf16)kv.z; o[3]=(__bf16)kv.w;
    *(bf16x4v*)(kb + (((size_t)(b * KH + kh) * S_ + s) * HD) + h4 * 4) = o;
}

// ---------------- QKV GEMM (128x128 tile, swizzled LDS) + fused RoPE epilogue ----------------
// blockIdx.y = head-block ny: 0..15 q heads, 16..19 k heads, 20..23 v heads.
__global__ __launch_bounds__(256, 2)
void qkv_gemm(const __bf16* __restrict__ A, const __bf16* __restrict__ BT,
              const int* __restrict__ pos,
              __bf16* __restrict__ qws, float* __restrict__ kout,
              float* __restrict__ vout, __bf16* __restrict__ kb,
              __bf16* __restrict__ vtb) {
    __shared__ __bf16 As[128 * 64];
    __shared__ __bf16 Bs[128 * 64];
    const int m0 = blockIdx.x * 128, ny = blockIdx.y;
    const int tid = threadIdx.x;
    const int wave = tid >> 6, lane = tid & 63;
    const int quad = lane >> 4, l16 = lane & 15;
    const int lrow = lane >> 3;
    const int lsw  = (lane & 7) ^ (lrow & 7);   // swizzled source chunk for staging

    f32x4v acc[2][8];
    for (int i = 0; i < 2; i++)
        for (int j = 0; j < 8; j++)
            acc[i][j] = (f32x4v){0.f, 0.f, 0.f, 0.f};

    const __bf16* Abase = A + (size_t)m0 * D_;
    const __bf16* Bbase = BT + (size_t)ny * 128 * D_;

    for (int k0 = 0; k0 < D_; k0 += 64) {
        for (int jj = 0; jj < 4; jj++) {
            int r = wave * 32 + jj * 8;
            async_copy16(As + (size_t)r * 64,
                         Abase + (size_t)(r + lrow) * D_ + k0 + lsw * 8);
            async_copy16(Bs + (size_t)r * 64,
                         Bbase + (size_t)(r + lrow) * D_ + k0 + lsw * 8);
        }
        __syncthreads();
        for (int ks = 0; ks < 2; ks++) {
            bf16x8v a[2], bb[8];
            for (int i = 0; i < 2; i++)
                a[i] = *(const bf16x8v*)(As + (wave * 32 + i * 16 + l16) * 64
                                         + (((ks * 4 + quad) ^ (l16 & 7)) * 8));
            for (int j = 0; j < 8; j++)
                bb[j] = *(const bf16x8v*)(Bs + (j * 16 + l16) * 64
                                          + (((ks * 4 + quad) ^ (l16 & 7)) * 8));
            for (int i = 0; i < 2; i++)
                for (int j = 0; j < 8; j++)
                    acc[i][j] = __builtin_amdgcn_mfma_f32_16x16x32_bf16(a[i], bb[j], acc[i][j], 0, 0, 0);
        }
        __syncthreads();
    }

    const float qscale = 0.08838834764831845f;   // 128^-0.5
    for (int i = 0; i < 2; i++)
        for (int r = 0; r < 4; r++) {
            int tau = m0 + wave * 32 + i * 16 + quad * 4 + r;
            int b = tau >> 10, t = tau & 1023;
            if (ny < 20) {  // rope path (q + k heads)
                float p = (float)pos[tau];
                for (int j = 0; j < 4; j++) {
                    int h = j * 16 + l16;                    // 0..63
                    float ang = p * __expf(-(float)h * (9.210340371976184f / 64.0f));
                    float sn = sinf(ang), cs = cosf(ang);
                    float x1 = acc[i][j][r], x2 = acc[i][j + 4][r];
                    float o1 = x1 * cs - x2 * sn;
                    float o2 = x2 * cs + x1 * sn;
                    if (ny < NH) {
                        size_t qo = ((size_t)tau * NH + ny) * HD;
                        qws[qo + h]      = (__bf16)(o1 * qscale);
                        qws[qo + h + 64] = (__bf16)(o2 * qscale);
                    } else {
                        int kh = ny - NH;
                        size_t ko = ((size_t)(b * S_ + TC_ + t) * KH + kh) * HD;
                        kout[ko + h]      = o1;
                        kout[ko + h + 64] = o2;
                        size_t kbo = ((size_t)(b * KH + kh) * S_ + TC_ + t) * HD;
                        kb[kbo + h]      = (__bf16)o1;
                        kb[kbo + h + 64] = (__bf16)o2;
                    }
                }
            } else {        // v heads: no rope; write vout f32 + transposed vtb bf16
                int kh = ny - 20;
                size_t vo = ((size_t)(b * S_ + TC_ + t) * KH + kh) * HD;
                size_t vt = ((size_t)(b * KH + kh)) * (size_t)HD * S_;
                for (int j = 0; j < 8; j++) {
                    int h = j * 16 + l16;
                    float v = acc[i][j][r];
                    vout[vo + h] = v;
                    vtb[vt + (size_t)h * S_ + TC_ + t] = (__bf16)v;
                }
            }
        }
}

// ---------------- out-proj GEMM (plain f32 C epilogue) ----------------
__global__ __launch_bounds__(256, 2)
void out_gemm(const __bf16* __restrict__ A, const __bf16* __restrict__ BT,
              float* __restrict__ C) {
    __shared__ __bf16 As[128 * 64];
    __shared__ __bf16 Bs[128 * 64];
    const int m0 = blockIdx.x * 128, n0 = blockIdx.y * 128;
    const int tid = threadIdx.x;
    const int wave = tid >> 6, lane = tid & 63;
    const int quad = lane >> 4, l16 = lane & 15;
    const int lrow = lane >> 3;
    const int lsw  = (lane & 7) ^ (lrow & 7);

    f32x4v acc[2][8];
    for (int i = 0; i < 2; i++)
        for (int j = 0; j < 8; j++)
            acc[i][j] = (f32x4v){0.f, 0.f, 0.f, 0.f};

    const __bf16* Abase = A + (size_t)m0 * D_;
    const __bf16* Bbase = BT + (size_t)n0 * D_;

    for (int k0 = 0; k0 < D_; k0 += 64) {
        for (int jj = 0; jj < 4; jj++) {
            int r = wave * 32 + jj * 8;
            async_copy16(As + (size_t)r * 64,
                         Abase + (size_t)(r + lrow) * D_ + k0 + lsw * 8);
            async_copy16(Bs + (size_t)r * 64,
                         Bbase + (size_t)(r + lrow) * D_ + k0 + lsw * 8);
        }
        __syncthreads();
        for (int ks = 0; ks < 2; ks++) {
            bf16x8v a[2], bb[8];
            for (int i = 0; i < 2; i++)
                a[i] = *(const bf16x8v*)(As + (wave * 32 + i * 16 + l16) * 64
                                         + (((ks * 4 + quad) ^ (l16 & 7)) * 8));
            for (int j = 0; j < 8; j++)
                bb[j] = *(const bf16x8v*)(Bs + (j * 16 + l16) * 64
                                          + (((ks * 4 + quad) ^ (l16 & 7)) * 8));
            for (int i = 0; i < 2; i++)
                for (int j = 0; j < 8; j++)
                    acc[i][j] = __builtin_amdgcn_mfma_f32_16x16x32_bf16(a[i], bb[j], acc[i][j], 0, 0, 0);
        }
        __syncthreads();
    }
    for (int i = 0; i < 2; i++)
        for (int r = 0; r < 4; r++) {
            int row = m0 + wave * 32 + i * 16 + quad * 4 + r;
            for (int j = 0; j < 8; j++)
                C[(size_t)row * D_ + n0 + j * 16 + l16] = acc[i][j][r];
        }
}

// ---------------- flash attention: independent wave-jobs, global B-frags, no-max softmax ----------------
// Job = (b,n, 32-row q-chunk c, S-third p). No inter-wave coupling; K/V MFMA
// fragments load straight from L2 (GQA heads share tiles; jid stride 96 = same XCD).
// No-max softmax: scores ~N(0,1) (max ~5.5 sigma << 88) so exp() cannot overflow;
// softmax is shift-invariant so result is exact. Row sums via ones-column MFMA.
__global__ __launch_bounds__(64, 3)
void attn(const __bf16* __restrict__ qws, const __bf16* __restrict__ kb,
          const __bf16* __restrict__ vtb,
          __bf16* __restrict__ op0, __bf16* __restrict__ op1, __bf16* __restrict__ op2,
          float* __restrict__ lb0, float* __restrict__ lb1, float* __restrict__ lb2) {
    __shared__ __bf16 Ps[32 * 72];

    const int jid = blockIdx.x;
    const int bn = jid / 96;
    const int rem = jid - bn * 96;
    const int c = rem / 3, p = rem - (rem / 3) * 3;
    const int b = bn >> 4, n = bn & 15, kh = n >> 2;
    const int t0 = c * 32;
    const int nT = (TC_ + t0 + 32 + 63) >> 6;     // S-tiles of 64
    const int q0 = (nT + 2) / 3;
    const int st_beg = p * q0;
    const int st_end = (st_beg + q0 < nT) ? (st_beg + q0) : nT;

    const int lane = threadIdx.x, quad = lane >> 4, l16 = lane & 15;

    // Q fragments resident: 32 rows x 128 h
    bf16x8v qf[2][4];
    {
        const __bf16* qbase = qws + ((size_t)(b * T_ + t0) * NH + n) * HD;
        for (int qt = 0; qt < 2; qt++)
            for (int ks = 0; ks < 4; ks++)
                qf[qt][ks] = *(const bf16x8v*)(qbase + (size_t)(qt * 16 + l16) * (NH * HD)
                                               + ks * 32 + quad * 8);
    }

    f32x4v o_acc[2][8], oL[2];
    for (int qt = 0; qt < 2; qt++) {
        oL[qt] = (f32x4v){0.f, 0.f, 0.f, 0.f};
        for (int j = 0; j < 8; j++) o_acc[qt][j] = (f32x4v){0.f, 0.f, 0.f, 0.f};
    }
    bf16x8v onesv;
    for (int e = 0; e < 8; e++) onesv[e] = (l16 == 0) ? (__bf16)1.0f : (__bf16)0.0f;

    const __bf16* kbase = kb  + ((size_t)(b * KH + kh)) * S_ * HD;
    const __bf16* vbase = vtb + ((size_t)(b * KH + kh)) * (size_t)HD * S_;

    for (int st = st_beg; st < st_end; st++) {
        const int s0 = st * 64;
        const bool maskt = (st == nT - 1);

        // QK^T one 16-col block at a time; exp; P -> LDS (wave-private)
        for (int j = 0; j < 4; j++) {
            f32x4v scj[2];
            scj[0] = (f32x4v){0.f, 0.f, 0.f, 0.f};
            scj[1] = (f32x4v){0.f, 0.f, 0.f, 0.f};
            const int s_abs = s0 + j * 16 + l16;
            for (int ks = 0; ks < 4; ks++) {
                bf16x8v bbv = *(const bf16x8v*)(kbase + (size_t)s_abs * HD + ks * 32 + quad * 8);
                for (int qt = 0; qt < 2; qt++)
                    scj[qt] = __builtin_amdgcn_mfma_f32_16x16x32_bf16(qf[qt][ks], bbv, scj[qt], 0, 0, 0);
            }
            for (int qt = 0; qt < 2; qt++)
                for (int r = 0; r < 4; r++) {
                    int q_abs = t0 + qt * 16 + quad * 4 + r;
                    float pv = (maskt && (s_abs > TC_ + q_abs)) ? 0.f : __expf(scj[qt][r]);
                    Ps[(qt * 16 + quad * 4 + r) * 72 + j * 16 + l16] = (__bf16)pv;
                }
        }
        __syncthreads();   // single-wave block: orders LDS writes vs cross-lane reads

        // PV + row-sum (ones column): o += P @ V
        for (int ks2 = 0; ks2 < 2; ks2++) {
            bf16x8v av[2];
            for (int qt = 0; qt < 2; qt++) {
                av[qt] = *(const bf16x8v*)(Ps + (qt * 16 + l16) * 72 + ks2 * 32 + quad * 8);
                oL[qt] = __builtin_amdgcn_mfma_f32_16x16x32_bf16(av[qt], onesv, oL[qt], 0, 0, 0);
            }
            for (int jh = 0; jh < 8; jh++) {
                bf16x8v bbv = *(const bf16x8v*)(vbase + (size_t)(jh * 16 + l16) * S_
                                                + s0 + ks2 * 32 + quad * 8);
                for (int qt = 0; qt < 2; qt++)
                    o_acc[qt][jh] = __builtin_amdgcn_mfma_f32_16x16x32_bf16(av[qt], bbv, o_acc[qt][jh], 0, 0, 0);
            }
        }
        __syncthreads();
    }

    // epilogue: unnormalized partial O (bf16) + row-sums l (f32, on l16==0 lanes)
    __bf16* op = (p == 0) ? op0 : (p == 1) ? op1 : op2;
    float*  lb = (p == 0) ? lb0 : (p == 1) ? lb1 : lb2;
    const size_t rbase = (size_t)bn * T_ + t0;
    for (int qt = 0; qt < 2; qt++)
        for (int r = 0; r < 4; r++) {
            int row = qt * 16 + quad * 4 + r;
            if (l16 == 0) lb[rbase + row] = oL[qt][r];
            for (int jh = 0; jh < 8; jh++)
                op[(rbase + row) * HD + jh * 16 + l16] = (__bf16)o_acc[qt][jh][r];
        }
}

// ---------------- merge 3 partials -> enc bf16 [b,t,n,h] ----------------
__global__ void merge(const __bf16* __restrict__ o0, const __bf16* __restrict__ o1,
                      const __bf16* __restrict__ o2,
                      const float* __restrict__ l0, const float* __restrict__ l1,
                      const float* __restrict__ l2,
                      __bf16* __restrict__ enc) {
    int gid = blockIdx.x * 256 + threadIdx.x;   // B*NH*T*HD/4 = 1048576
    int row = gid >> 5, c4 = (gid & 31) * 4;
    float inv = 1.0f / (l0[row] + l1[row] + l2[row]);
    bf16x4v a = *(const bf16x4v*)(o0 + (size_t)row * HD + c4);
    bf16x4v c = *(const bf16x4v*)(o1 + (size_t)row * HD + c4);
    bf16x4v d = *(const bf16x4v*)(o2 + (size_t)row * HD + c4);
    int b = row >> 14, n = (row >> 10) & 15, t = row & 1023;
    bf16x4v e;
    for (int i = 0; i < 4; i++)
        e[i] = (__bf16)(((float)a[i] + (float)c[i] + (float)d[i]) * inv);
    *(bf16x4v*)(enc + (((size_t)(b * T_ + t) * NH + n) * HD) + c4) = e;
}

extern "C" void kernel_launch(void* const* d_in, const int* in_sizes, int n_in,
                              void* d_out, int out_size, void* d_ws, size_t ws_size,
                              hipStream_t stream) {
    const float* x       = (const float*)d_in[0];
    const int*   pos     = (const int*)d_in[1];
    const float* cache_k = (const float*)d_in[3];
    const float* cache_v = (const float*)d_in[4];
    const float* w_q     = (const float*)d_in[5];
    const float* w_kv    = (const float*)d_in[6];
    const float* w_out   = (const float*)d_in[7];

    float* out  = (float*)d_out;
    float* kout = out  + (size_t)B_ * T_ * D_;
    float* vout = kout + (size_t)B_ * S_ * KH * HD;

    char* ws = (char*)d_ws;
    __bf16* xb   = (__bf16*)ws;  ws += (size_t)B_ * T_ * D_ * 2;        // 8.4 MB
    __bf16* wt   = (__bf16*)ws;  ws += (size_t)3072 * D_ * 2;           // 12.6 MB (dead after qkv_gemm)
    __bf16* wot  = (__bf16*)ws;  ws += (size_t)D_ * NH * HD * 2;        // 8.4 MB
    char*   scr  = ws;           ws += (size_t)B_ * T_ * 3072 * 4;      // 25.2 MB (attn O partials)
    __bf16* qws  = (__bf16*)ws;  ws += (size_t)B_ * T_ * NH * HD * 2;   // 8.4 MB
    __bf16* kbuf = (__bf16*)ws;  ws += (size_t)B_ * S_ * KH * HD * 2;   // 4.2 MB [B,K,S,H]
    __bf16* vtb  = (__bf16*)ws;  ws += (size_t)B_ * S_ * KH * HD * 2;   // 4.2 MB [B,K,H,S]
    __bf16* enc  = (__bf16*)ws;                                          // 8.4 MB

    const size_t ON = (size_t)B_ * NH * T_ * HD;      // 4,194,304
    __bf16* op0 = (__bf16*)scr;
    __bf16* op1 = op0 + ON;
    __bf16* op2 = op1 + ON;
    // l buffers alias wt (dead after qkv_gemm): 3 x 128 KB
    float* lb0 = (float*)wt;
    float* lb1 = lb0 + (size_t)B_ * NH * T_;
    float* lb2 = lb1 + (size_t)B_ * NH * T_;

    cvt_x<<<4096, 256, 0, stream>>>(x, xb);
    tp_w<<<dim3(4, 64, 16), dim3(32, 8), 0, stream>>>(w_q, wt);
    tp_w<<<dim3(4, 64, 8),  dim3(32, 8), 0, stream>>>(w_kv, wt + (size_t)16 * HD * D_);
    tp_wout<<<dim3(64, 4, 16), dim3(32, 8), 0, stream>>>(w_out, wot);
    copy_cache<<<1024, 256, 0, stream>>>((const float4*)cache_k, (const float4*)cache_v, kout, vout, kbuf);
    tp_v<<<dim3(4, 32, 8), dim3(32, 8), 0, stream>>>(cache_v, vtb);
    qkv_gemm<<<dim3(16, 24), 256, 0, stream>>>(xb, wt, pos, qws, kout, vout, kbuf, vtb);
    attn<<<3072, 64, 0, stream>>>(qws, kbuf, vtb, op0, op1, op2, lb0, lb1, lb2);
    merge<<<4096, 256, 0, stream>>>(op0, op1, op2, lb0, lb1, lb2, enc);
    out_gemm<<<dim3(16, 16), 256, 0, stream>>>(enc, wot, out);
}

// Round 6
// 286.587 us; speedup vs baseline: 1.6433x; 1.6433x over previous
//
#include <hip/hip_runtime.h>

#define B_  2
#define T_  1024
#define D_  2048
#define NH  16
#define KH  4
#define HD  128
#define TC_ 1024
#define S_  2048

typedef __bf16 bf16x4v __attribute__((ext_vector_type(4)));
typedef __bf16 bf16x8v __attribute__((ext_vector_type(8)));
typedef float  f32x4v  __attribute__((ext_vector_type(4)));

__device__ __forceinline__ void async_copy16(void* lds, const void* g) {
    __builtin_amdgcn_global_load_lds(
        (__attribute__((address_space(1))) void*)g,
        (__attribute__((address_space(3))) void*)lds, 16, 0, 0);
}

// ---------------- x fp32 -> bf16 ----------------
__global__ void cvt_x(const float* __restrict__ x, __bf16* __restrict__ xb) {
    int i = (blockIdx.x * 256 + threadIdx.x) * 4;
    float4 v = *(const float4*)(x + i);
    bf16x4v o; o[0]=(__bf16)v.x; o[1]=(__bf16)v.y; o[2]=(__bf16)v.z; o[3]=(__bf16)v.w;
    *(bf16x4v*)(xb + i) = o;
}

// ---------------- weight transposes ----------------
__global__ void tp_w(const float* __restrict__ in, __bf16* __restrict__ out) {
    __shared__ float tile[32][33];
    int h0 = blockIdx.x * 32;
    int d0 = blockIdx.y * 32;
    const float* ip = in + (size_t)blockIdx.z * (D_ * HD);
    __bf16* op = out + (size_t)blockIdx.z * (D_ * HD);
    int tx = threadIdx.x, ty = threadIdx.y;
    for (int i = 0; i < 32; i += 8)
        tile[ty + i][tx] = ip[(size_t)(d0 + ty + i) * HD + h0 + tx];
    __syncthreads();
    for (int i = 0; i < 32; i += 8)
        op[(size_t)(h0 + ty + i) * D_ + d0 + tx] = (__bf16)tile[tx][ty + i];
}

__global__ void tp_wout(const float* __restrict__ in, __bf16* __restrict__ out) {
    __shared__ float tile[32][33];
    int d0 = blockIdx.x * 32;
    int h0 = blockIdx.y * 32;
    int n  = blockIdx.z;
    const float* ip = in + (size_t)n * (HD * D_);
    int tx = threadIdx.x, ty = threadIdx.y;
    for (int i = 0; i < 32; i += 8)
        tile[ty + i][tx] = ip[(size_t)(h0 + ty + i) * D_ + d0 + tx];
    __syncthreads();
    for (int i = 0; i < 32; i += 8)
        out[(size_t)(d0 + ty + i) * (NH * HD) + n * HD + h0 + tx] = (__bf16)tile[tx][ty + i];
}

// v out region fp32 [B][S][K][H] -> vtb bf16 [B][K][H][S]
__global__ void tp_v(const float* __restrict__ vout, __bf16* __restrict__ vtb) {
    __shared__ float tile[32][33];
    int z = blockIdx.z; int b = z / KH, kh = z % KH;
    int h0 = blockIdx.x * 32;
    int s0 = blockIdx.y * 32;
    const float* ip = vout + ((size_t)b * S_ * KH + kh) * HD;
    int tx = threadIdx.x, ty = threadIdx.y;
    for (int i = 0; i < 32; i += 8)
        tile[ty + i][tx] = ip[(size_t)(s0 + ty + i) * (KH * HD) + h0 + tx];
    __syncthreads();
    __bf16* op = vtb + ((size_t)b * KH + kh) * (size_t)HD * S_;
    for (int i = 0; i < 32; i += 8)
        op[(size_t)(h0 + ty + i) * S_ + s0 + tx] = (__bf16)tile[tx][ty + i];
}

// ---------------- cache copy (fp32 exact) + bf16 K-cache ----------------
__global__ void copy_cache(const float4* __restrict__ ck, const float4* __restrict__ cv,
                           float* __restrict__ kout, float* __restrict__ vout,
                           __bf16* __restrict__ kb) {
    int i = blockIdx.x * 256 + threadIdx.x;     // 262144 total
    int b = i >> 17;
    int r = i & 131071;
    float4 kv = ck[i];
    ((float4*)(kout + (size_t)b * S_ * KH * HD))[r] = kv;
    ((float4*)(vout + (size_t)b * S_ * KH * HD))[r] = cv[i];
    int h4 = r & 31;
    int kh = (r >> 5) & 3;
    int s  = r >> 7;
    bf16x4v o; o[0]=(__bf16)kv.x; o[1]=(__bf16)kv.y; o[2]=(__bf16)kv.z; o[3]=(__bf16)kv.w;
    *(bf16x4v*)(kb + (((size_t)(b * KH + kh) * S_ + s) * HD) + h4 * 4) = o;
}

// ---------------- 128x128-tile bf16 GEMM, C = A @ BT^T, K=2048, swizzled LDS ----------------
__global__ __launch_bounds__(256, 2)
void gemm_bt(const __bf16* __restrict__ A, const __bf16* __restrict__ BT,
             float* __restrict__ C, int ldc) {
    __shared__ __bf16 As[128 * 64];
    __shared__ __bf16 Bs[128 * 64];
    const int m0 = blockIdx.x * 128, n0 = blockIdx.y * 128;
    const int tid = threadIdx.x;
    const int wave = tid >> 6, lane = tid & 63;
    const int quad = lane >> 4, l16 = lane & 15;
    const int wm = (wave & 1) * 64, wn = (wave >> 1) * 64;
    const int lrow = lane >> 3;
    const int lsw  = (lane & 7) ^ (lrow & 7);   // swizzled source chunk: slot(row,c) holds c^(row&7)

    f32x4v acc[4][4];
    for (int i = 0; i < 4; i++)
        for (int j = 0; j < 4; j++)
            acc[i][j] = (f32x4v){0.f, 0.f, 0.f, 0.f};

    const __bf16* Abase = A + (size_t)m0 * D_;
    const __bf16* Bbase = BT + (size_t)n0 * D_;

    for (int k0 = 0; k0 < D_; k0 += 64) {
        for (int j = 0; j < 4; j++) {
            int r = wave * 32 + j * 8;
            async_copy16(As + (size_t)r * 64,
                         Abase + (size_t)(r + lrow) * D_ + k0 + lsw * 8);
            async_copy16(Bs + (size_t)r * 64,
                         Bbase + (size_t)(r + lrow) * D_ + k0 + lsw * 8);
        }
        __syncthreads();
        for (int ks = 0; ks < 2; ks++) {
            const int ch = ((ks * 4 + quad) ^ (l16 & 7)) * 8;
            bf16x8v a[4], b[4];
            for (int i = 0; i < 4; i++)
                a[i] = *(const bf16x8v*)(As + (wm + i * 16 + l16) * 64 + ch);
            for (int j = 0; j < 4; j++)
                b[j] = *(const bf16x8v*)(Bs + (wn + j * 16 + l16) * 64 + ch);
            for (int i = 0; i < 4; i++)
                for (int j = 0; j < 4; j++)
                    acc[i][j] = __builtin_amdgcn_mfma_f32_16x16x32_bf16(a[i], b[j], acc[i][j], 0, 0, 0);
        }
        __syncthreads();
    }
    for (int i = 0; i < 4; i++)
        for (int j = 0; j < 4; j++)
            for (int r = 0; r < 4; r++) {
                int row = m0 + wm + i * 16 + quad * 4 + r;
                int col = n0 + wn + j * 16 + l16;
                C[(size_t)row * ldc + col] = acc[i][j][r];
            }
}

// ---------------- RoPE + scatter QKV (+ bf16 new-K) ----------------
__global__ void finish_rope(const float* __restrict__ proj, const int* __restrict__ pos,
                            __bf16* __restrict__ qws, float* __restrict__ kout,
                            float* __restrict__ vout, __bf16* __restrict__ kb) {
    const int tau = blockIdx.x;
    const int b = tau >> 10, t = tau & 1023;
    const float p = (float)pos[tau];
    const float* pr = proj + (size_t)tau * 3072;
    const float qscale = 0.08838834764831845f;   // 128^-0.5
    for (int idx = threadIdx.x; idx < (NH + KH) * 64; idx += 256) {
        int head = idx >> 6;
        int hh = idx & 63;
        float ang = p * __expf(-(float)hh * (9.210340371976184f / 64.0f));
        float sn, cs;
        __sincosf(ang, &sn, &cs);
        if (head < NH) {
            float x1 = pr[head * HD + hh], x2 = pr[head * HD + hh + 64];
            size_t qo = ((size_t)tau * NH + head) * HD;
            qws[qo + hh]      = (__bf16)((x1 * cs - x2 * sn) * qscale);
            qws[qo + hh + 64] = (__bf16)((x2 * cs + x1 * sn) * qscale);
        } else {
            int kh = head - NH;
            float x1 = pr[2048 + kh * HD + hh], x2 = pr[2048 + kh * HD + hh + 64];
            float k1 = x1 * cs - x2 * sn, k2 = x2 * cs + x1 * sn;
            size_t ko = ((size_t)(b * S_ + TC_ + t) * KH + kh) * HD;
            kout[ko + hh]      = k1;
            kout[ko + hh + 64] = k2;
            size_t kbo = ((size_t)(b * KH + kh) * S_ + TC_ + t) * HD;
            kb[kbo + hh]      = (__bf16)k1;
            kb[kbo + hh + 64] = (__bf16)k2;
        }
    }
    for (int idx = threadIdx.x; idx < KH * HD; idx += 256) {
        int kh = idx >> 7, h = idx & 127;
        vout[((size_t)(b * S_ + TC_ + t) * KH + kh) * HD + h] = pr[2560 + kh * HD + h];
    }
}

// ---------------- flash attention (8 waves, XOR-swizzled LDS) ----------------
__global__ __launch_bounds__(512, 1)
void attn(const __bf16* __restrict__ qws, const __bf16* __restrict__ kb,
          const __bf16* __restrict__ vtb, __bf16* __restrict__ enc) {
    __shared__ __bf16 Qs[128 * 128];
    __shared__ __bf16 Ks[128 * 128];
    __shared__ __bf16 Vs[128 * 128];
    __shared__ __bf16 Ps[128 * 128];

    const int t0 = blockIdx.x * 128;
    const int n  = blockIdx.y;
    const int b  = blockIdx.z;
    const int kh = n / (NH / KH);
    const int tid = threadIdx.x, wave = tid >> 6, lane = tid & 63;
    const int quad = lane >> 4, l16 = lane & 15;
    const int wm = wave * 16;
    const int arow = lane >> 4;
    const int acol = lane & 15;

    // Q tile [128 t][128 h], swizzled source
    {
        const __bf16* qtile = qws + ((size_t)(b * T_ + t0) * NH + n) * HD;
        for (int jj = 0; jj < 4; jj++) {
            int r0 = wm + jj * 4;
            int row = r0 + arow;
            async_copy16(Qs + (size_t)r0 * 128,
                         qtile + (size_t)row * (NH * HD) + ((acol ^ (row & 15)) * 8));
        }
    }

    float m_run[4], l_run[4];
    f32x4v o_acc[8];
    for (int r = 0; r < 4; r++) { m_run[r] = -INFINITY; l_run[r] = 0.f; }
    for (int j = 0; j < 8; j++) o_acc[j] = (f32x4v){0.f, 0.f, 0.f, 0.f};

    const int nS = (TC_ + t0 + 128) >> 7;
    const __bf16* kbase = kb  + ((size_t)(b * KH + kh)) * S_ * HD;
    const __bf16* vbase = vtb + ((size_t)(b * KH + kh)) * (size_t)HD * S_;

    for (int st = 0; st < nS; st++) {
        const int s0 = st * 128;
        {
            const __bf16* ktile = kbase + (size_t)s0 * HD;
            for (int jj = 0; jj < 4; jj++) {
                int r0 = wm + jj * 4;
                int row = r0 + arow;
                async_copy16(Ks + (size_t)r0 * 128,
                             ktile + (size_t)row * HD + ((acol ^ (row & 15)) * 8));
            }
        }
        {
            const __bf16* vtile = vbase + s0;
            for (int jj = 0; jj < 4; jj++) {
                int r0 = wm + jj * 4;
                int row = r0 + arow;
                async_copy16(Vs + (size_t)r0 * 128,
                             vtile + (size_t)row * S_ + ((acol ^ (row & 15)) * 8));
            }
        }
        __syncthreads();

        // QK^T: this wave's 16 rows x 128 cols
        f32x4v sc[8];
        for (int j = 0; j < 8; j++) sc[j] = (f32x4v){0.f, 0.f, 0.f, 0.f};
        for (int ks = 0; ks < 4; ks++) {
            int ch = (ks * 4 + quad) ^ l16;
            bf16x8v a = *(const bf16x8v*)(Qs + (wm + l16) * 128 + ch * 8);
            bf16x8v bb[8];
            for (int j = 0; j < 8; j++)
                bb[j] = *(const bf16x8v*)(Ks + (j * 16 + l16) * 128 + ch * 8);
            for (int j = 0; j < 8; j++)
                sc[j] = __builtin_amdgcn_mfma_f32_16x16x32_bf16(a, bb[j], sc[j], 0, 0, 0);
        }

        // causal mask (diagonal tile only: s0 == TC + t0)
        if (st == nS - 1) {
            for (int j = 0; j < 8; j++)
                for (int r = 0; r < 4; r++) {
                    int row = wm + quad * 4 + r;
                    int col = j * 16 + l16;
                    if (col > row) sc[j][r] = -3.0e38f;
                }
        }

        // online softmax
        for (int r = 0; r < 4; r++) {
            float mx = sc[0][r];
            for (int j = 1; j < 8; j++) mx = fmaxf(mx, sc[j][r]);
            for (int off = 8; off >= 1; off >>= 1) mx = fmaxf(mx, __shfl_xor(mx, off, 64));
            mx = fmaxf(mx, m_run[r]);
            float alpha = __expf(m_run[r] - mx);
            m_run[r] = mx;
            float s = 0.f;
            for (int j = 0; j < 8; j++) {
                float pv = __expf(sc[j][r] - mx);
                sc[j][r] = pv;
                s += pv;
            }
            for (int off = 8; off >= 1; off >>= 1) s += __shfl_xor(s, off, 64);
            l_run[r] = l_run[r] * alpha + s;
            for (int j = 0; j < 8; j++) o_acc[j][r] *= alpha;
        }

        // P -> LDS (C-layout -> A-layout), swizzled chunks
        for (int j = 0; j < 8; j++)
            for (int r = 0; r < 4; r++) {
                int row = wm + quad * 4 + r;
                int c = (j * 2 + (l16 >> 3)) ^ (row & 15);
                Ps[row * 128 + c * 8 + (l16 & 7)] = (__bf16)sc[j][r];
            }
        __syncthreads();

        // PV: o_acc += P @ V
        for (int ks = 0; ks < 4; ks++) {
            int ch = (ks * 4 + quad) ^ l16;
            bf16x8v a = *(const bf16x8v*)(Ps + (wm + l16) * 128 + ch * 8);
            bf16x8v bb[8];
            for (int j = 0; j < 8; j++)
                bb[j] = *(const bf16x8v*)(Vs + (j * 16 + l16) * 128 + ch * 8);
            for (int j = 0; j < 8; j++)
                o_acc[j] = __builtin_amdgcn_mfma_f32_16x16x32_bf16(a, bb[j], o_acc[j], 0, 0, 0);
        }
        __syncthreads();
    }

    // epilogue: enc[b,t,n,h] bf16
    for (int r = 0; r < 4; r++) {
        float inv = 1.0f / l_run[r];
        int row = wm + quad * 4 + r;
        for (int j = 0; j < 8; j++) {
            int col = j * 16 + l16;
            enc[((size_t)(b * T_ + t0 + row) * NH + n) * HD + col] =
                (__bf16)(o_acc[j][r] * inv);
        }
    }
}

extern "C" void kernel_launch(void* const* d_in, const int* in_sizes, int n_in,
                              void* d_out, int out_size, void* d_ws, size_t ws_size,
                              hipStream_t stream) {
    const float* x       = (const float*)d_in[0];
    const int*   pos     = (const int*)d_in[1];
    const float* cache_k = (const float*)d_in[3];
    const float* cache_v = (const float*)d_in[4];
    const float* w_q     = (const float*)d_in[5];
    const float* w_kv    = (const float*)d_in[6];
    const float* w_out   = (const float*)d_in[7];

    float* out  = (float*)d_out;
    float* kout = out  + (size_t)B_ * T_ * D_;
    float* vout = kout + (size_t)B_ * S_ * KH * HD;

    char* ws = (char*)d_ws;
    __bf16* xb   = (__bf16*)ws;  ws += (size_t)B_ * T_ * D_ * 2;
    __bf16* wt   = (__bf16*)ws;  ws += (size_t)3072 * D_ * 2;
    __bf16* wot  = (__bf16*)ws;  ws += (size_t)D_ * NH * HD * 2;
    float*  proj = (float*)ws;   ws += (size_t)B_ * T_ * 3072 * 4;
    __bf16* qws  = (__bf16*)ws;  ws += (size_t)B_ * T_ * NH * HD * 2;
    __bf16* kbuf = (__bf16*)ws;  ws += (size_t)B_ * S_ * KH * HD * 2;
    __bf16* vtb  = (__bf16*)ws;  ws += (size_t)B_ * S_ * KH * HD * 2;
    __bf16* enc  = (__bf16*)ws;

    cvt_x<<<4096, 256, 0, stream>>>(x, xb);
    tp_w<<<dim3(4, 64, 16), dim3(32, 8), 0, stream>>>(w_q, wt);
    tp_w<<<dim3(4, 64, 8),  dim3(32, 8), 0, stream>>>(w_kv, wt + (size_t)16 * HD * D_);
    tp_wout<<<dim3(64, 4, 16), dim3(32, 8), 0, stream>>>(w_out, wot);
    copy_cache<<<1024, 256, 0, stream>>>((const float4*)cache_k, (const float4*)cache_v, kout, vout, kbuf);
    gemm_bt<<<dim3(16, 24), 256, 0, stream>>>(xb, wt, proj, 3072);
    finish_rope<<<2048, 256, 0, stream>>>(proj, pos, qws, kout, vout, kbuf);
    tp_v<<<dim3(4, 64, 8), dim3(32, 8), 0, stream>>>(vout, vtb);
    attn<<<dim3(8, 16, 2), 512, 0, stream>>>(qws, kbuf, vtb, enc);
    gemm_bt<<<dim3(16, 16), 256, 0, stream>>>(enc, wot, out, 2048);
}